// Round 1
// baseline (235.146 us; speedup 1.0000x reference)
//
#include <hip/hip_runtime.h>

#define BB 128
#define LL 336
#define CC 862
#define PRED 96
#define WIN 12
#define S_IN 28
#define S_OUT 8
#define CT 32
#define NTILES ((CC + CT - 1) / CT)   // 27

#define SQRT12F 3.4641016151377544f

// -Sb(t)/sqrt(12), Sb(t) = 2*sum_{k=1..5} sin(pi*k*t/6)   (exact closed forms)
__device__ const float COEFP[12] = {
    0.0f, -2.1547005383792515f, 0.0f, -0.5773502691896258f,
    0.0f, -0.15470053837925146f, 0.0f, 0.15470053837925146f,
    0.0f,  0.5773502691896258f, 0.0f,  2.1547005383792515f
};

// ---- prep kernels (tiny, write transposed weights into ws) ----

__global__ void prep_transpose(const float* __restrict__ wA, const float* __restrict__ wP,
                               float* __restrict__ wAT, float* __restrict__ wPT) {
    int i = blockIdx.x * 256 + threadIdx.x;          // i indexes [p][s][c]
    if (i >= S_OUT * S_IN * CC) return;
    int c = i % CC;
    int ps = i / CC;
    int s = ps % S_IN;
    int p = ps / S_IN;
    int src = (c * S_OUT + p) * S_IN + s;
    wAT[i] = wA[src];
    wPT[i] = wP[src];
}

__global__ void prep_mcoef(const float* __restrict__ wA, float* __restrict__ mcoefT) {
    int i = blockIdx.x * 256 + threadIdx.x;          // [p][c]
    if (i >= S_OUT * CC) return;
    int c = i % CC;
    int p = i / CC;
    float s = 0.f;
    for (int k = 0; k < S_IN; ++k) s += wA[(c * S_OUT + p) * S_IN + k];
    mcoefT[i] = 1.0f - s;
}

__global__ void prep_bias(const float* __restrict__ bA, const float* __restrict__ bP,
                          float* __restrict__ biasv) {
    int i = blockIdx.x * 256 + threadIdx.x;          // [t][p][c]
    if (i >= 12 * S_OUT * CC) return;
    int c = i % CC;
    int tp = i / CC;
    int p = tp % S_OUT;
    int t = tp / S_OUT;
    float v = COEFP[t] * bP[c * S_OUT + p];
    if (t == 0) v += SQRT12F * bA[c * S_OUT + p];
    biasv[i] = v;
}

// ---- fused main kernel ----

template <bool TRANS>
__global__ __launch_bounds__(256) void fused_kernel(
    const float* __restrict__ x,
    const float* __restrict__ wAT, const float* __restrict__ wPT,
    const float* __restrict__ mcoefT, const float* __restrict__ biasv,
    const float* __restrict__ wA_raw, const float* __restrict__ wP_raw,
    const float* __restrict__ bA, const float* __restrict__ bP,
    float* __restrict__ out)
{
    __shared__ float sx[LL][CT];      // 43008 B
    __shared__ float spart[8][CT];
    __shared__ float smean[CT];

    const int ctile = blockIdx.x;
    const int b     = blockIdx.y;
    const int c0    = ctile * CT;
    const int NC    = min(CT, CC - c0);   // 32 or 30 (always even)
    const int tid   = threadIdx.x;

    // stage x[b, :, c0:c0+NC] into LDS (float2 per thread, coalesced over c)
    {
        const int cp = tid & 15;        // float2 column pair 0..15
        const int l0 = tid >> 4;        // 0..15
        const int cc = 2 * cp;
        for (int l = l0; l < LL; l += 16) {
            float2 v = make_float2(0.f, 0.f);
            if (cc < NC) {
                const float* src = x + ((size_t)b * LL + l) * CC + c0 + cc;
                v = *reinterpret_cast<const float2*>(src);
            }
            sx[l][cc]     = v.x;
            sx[l][cc + 1] = v.y;
        }
    }
    __syncthreads();

    // per-channel mean over L
    {
        const int cc = tid & 31, r = tid >> 5;
        float s = 0.f;
        for (int l = r; l < LL; l += 8) s += sx[l][cc];
        spart[r][cc] = s;
    }
    __syncthreads();
    if (tid < CT) {
        float s = 0.f;
        #pragma unroll
        for (int r = 0; r < 8; ++r) s += spart[r][tid];
        smean[tid] = s * (1.0f / LL);
    }
    __syncthreads();

    const int cc   = tid & 31;
    const int pair = tid >> 5;          // 0..7, only 0..6 used
    if (pair >= 7 || cc >= NC) return;
    const int c  = c0 + cc;
    const int t  = pair;
    const int tr = (12 - t) % 12;       // pair 0 -> 0, pair 6 -> 6

    float u[S_IN], v[S_IN];
    #pragma unroll
    for (int s = 0; s < S_IN; ++s) {
        float xt = sx[s * WIN + t][cc];
        float xr = sx[s * WIN + tr][cc];
        u[s] = xt + xr;
        v[s] = xt - xr;
    }
    const float mean = smean[cc];

    #pragma unroll
    for (int p = 0; p < S_OUT; ++p) {
        float A = 0.f, P = 0.f, mc;
        float bias_t, bias_r;
        if (TRANS) {
            const float* wa = wAT + (size_t)(p * S_IN) * CC + c;
            const float* wp = wPT + (size_t)(p * S_IN) * CC + c;
            #pragma unroll
            for (int s = 0; s < S_IN; ++s) {
                A = fmaf(wa[(size_t)s * CC], u[s], A);
                P = fmaf(wp[(size_t)s * CC], v[s], P);
            }
            mc = mcoefT[p * CC + c];
            bias_t = biasv[(t * S_OUT + p) * CC + c];
            bias_r = biasv[(tr * S_OUT + p) * CC + c];
        } else {
            const float* wa = wA_raw + (size_t)(c * S_OUT + p) * S_IN;
            const float* wp = wP_raw + (size_t)(c * S_OUT + p) * S_IN;
            float sw = 0.f;
            #pragma unroll
            for (int s = 0; s < S_IN; ++s) {
                float was = wa[s];
                A = fmaf(was, u[s], A);
                P = fmaf(wp[s], v[s], P);
                sw += was;
            }
            mc = 1.0f - sw;
            float ba = bA[c * S_OUT + p], bp = bP[c * S_OUT + p];
            bias_t = COEFP[t] * bp + (t == 0 ? SQRT12F * ba : 0.f);
            bias_r = COEFP[tr] * bp;   // tr==0 only when t==0 (then unused)
        }
        const float mb = mean * mc;
        float ot = 0.5f * (A + P) + mb + bias_t;
        out[((size_t)b * PRED + p * WIN + t) * CC + c] = ot;
        if (t != tr) {
            float orr = 0.5f * (A - P) + mb + bias_r;
            out[((size_t)b * PRED + p * WIN + tr) * CC + c] = orr;
        }
    }
}

extern "C" void kernel_launch(void* const* d_in, const int* in_sizes, int n_in,
                              void* d_out, int out_size, void* d_ws, size_t ws_size,
                              hipStream_t stream) {
    const float* x  = (const float*)d_in[0];
    const float* wA = (const float*)d_in[1];
    const float* bA = (const float*)d_in[2];
    const float* wP = (const float*)d_in[3];
    const float* bP = (const float*)d_in[4];
    float* out = (float*)d_out;

    const size_t nT  = (size_t)S_OUT * S_IN * CC;   // 193088
    const size_t nM  = (size_t)S_OUT * CC;          // 6896
    const size_t nBv = (size_t)12 * S_OUT * CC;     // 82752
    const size_t need = (2 * nT + nM + nBv) * sizeof(float);

    dim3 grid(NTILES, BB);

    if (ws_size >= need) {
        float* wAT    = (float*)d_ws;
        float* wPT    = wAT + nT;
        float* mcoefT = wPT + nT;
        float* biasv  = mcoefT + nM;

        prep_transpose<<<(int)((nT + 255) / 256), 256, 0, stream>>>(wA, wP, wAT, wPT);
        prep_mcoef<<<(int)((nM + 255) / 256), 256, 0, stream>>>(wA, mcoefT);
        prep_bias<<<(int)((nBv + 255) / 256), 256, 0, stream>>>(bA, bP, biasv);

        fused_kernel<true><<<grid, 256, 0, stream>>>(
            x, wAT, wPT, mcoefT, biasv,
            nullptr, nullptr, nullptr, nullptr, out);
    } else {
        fused_kernel<false><<<grid, 256, 0, stream>>>(
            x, nullptr, nullptr, nullptr, nullptr,
            wA, wP, bA, bP, out);
    }
}

// Round 2
// 126.419 us; speedup vs baseline: 1.8601x; 1.8601x over previous
//
#include <hip/hip_runtime.h>

#define BB 128
#define LL 336
#define CC 862
#define PRED 96
#define WIN 12
#define S_IN 28
#define S_OUT 8
#define CT 32
#define NTILES ((CC + CT - 1) / CT)   // 27

#define SQRT12F 3.4641016151377544f

// -Sb(t)/sqrt(12), Sb(t) = 2*sum_{k=1..5} sin(pi*k*t/6)   (exact closed forms)
__device__ const float COEFP[12] = {
    0.0f, -2.1547005383792515f, 0.0f, -0.5773502691896258f,
    0.0f, -0.15470053837925146f, 0.0f, 0.15470053837925146f,
    0.0f,  0.5773502691896258f, 0.0f,  2.1547005383792515f
};

// ---- prep kernels (tiny, write repacked weights into ws) ----

// wA4/wP4 layout: [p][c][s] (s contiguous, 28 floats = 112 B per (p,c), 16B-aligned)
__global__ void prep_w4(const float* __restrict__ wA, const float* __restrict__ wP,
                        float* __restrict__ wA4, float* __restrict__ wP4) {
    int i = blockIdx.x * 256 + threadIdx.x;          // i = (p*CC + c)*28 + s
    if (i >= S_OUT * CC * S_IN) return;
    int s  = i % S_IN;
    int pc = i / S_IN;
    int c  = pc % CC;
    int p  = pc / CC;
    int src = (c * S_OUT + p) * S_IN + s;
    wA4[i] = wA[src];
    wP4[i] = wP[src];
}

__global__ void prep_mcoef(const float* __restrict__ wA, float* __restrict__ mcoefT) {
    int i = blockIdx.x * 256 + threadIdx.x;          // [p][c]
    if (i >= S_OUT * CC) return;
    int c = i % CC;
    int p = i / CC;
    float s = 0.f;
    for (int k = 0; k < S_IN; ++k) s += wA[(c * S_OUT + p) * S_IN + k];
    mcoefT[i] = 1.0f - s;
}

__global__ void prep_bias(const float* __restrict__ bA, const float* __restrict__ bP,
                          float* __restrict__ biasv) {
    int i = blockIdx.x * 256 + threadIdx.x;          // [t][p][c]
    if (i >= 12 * S_OUT * CC) return;
    int c = i % CC;
    int tp = i / CC;
    int p = tp % S_OUT;
    int t = tp / S_OUT;
    float v = COEFP[t] * bP[c * S_OUT + p];
    if (t == 0) v += SQRT12F * bA[c * S_OUT + p];
    biasv[i] = v;
}

// ---- fused main kernel (no x staging) ----
// thread = (cc in 0..31, pair in 0..7); pairs 0..6 active (t = pair, tr = (12-t)%12)

template <bool TRANS>
__global__ __launch_bounds__(256) void fused2(
    const float* __restrict__ x,
    const float* __restrict__ wA4, const float* __restrict__ wP4,
    const float* __restrict__ mcoefT, const float* __restrict__ biasv,
    const float* __restrict__ wA_raw, const float* __restrict__ wP_raw,
    const float* __restrict__ bAr, const float* __restrict__ bPr,
    float* __restrict__ out)
{
    __shared__ float ssum[7][CT];    // 896 B

    const int b    = blockIdx.y;
    const int c0   = blockIdx.x * CT;
    const int NC   = min(CT, CC - c0);
    const int tid  = threadIdx.x;
    const int cc   = tid & 31;
    const int pair = tid >> 5;       // 0..7
    const int c    = c0 + cc;
    const int t    = (pair < 7) ? pair : 0;
    const int tr   = (12 - t) % 12;  // t==0 -> 0, t==6 -> 6
    const bool active = (pair < 7) && (cc < NC);

    float u[S_IN], v[S_IN];
    const float* xb = x + ((size_t)b * LL) * CC + c;
    if (active) {
        #pragma unroll
        for (int s = 0; s < S_IN; ++s) {
            float xt = xb[(size_t)(s * WIN + t)  * CC];
            float xr = xb[(size_t)(s * WIN + tr) * CC];
            u[s] = xt + xr;
            v[s] = xt - xr;
        }
    } else {
        #pragma unroll
        for (int s = 0; s < S_IN; ++s) { u[s] = 0.f; v[s] = 0.f; }
    }

    // per-channel mean: sum over L decomposes into the pair u-sums
    if (pair < 7) {
        float su = 0.f;
        #pragma unroll
        for (int s = 0; s < S_IN; ++s) su += u[s];
        ssum[pair][cc] = (t == 0 || t == 6) ? 0.5f * su : su;
    }
    __syncthreads();
    float mean = 0.f;
    #pragma unroll
    for (int r = 0; r < 7; ++r) mean += ssum[r][cc];
    mean *= (1.0f / LL);

    if (!active) return;

    float* ob = out + ((size_t)b * PRED) * CC + c;

    #pragma unroll 2
    for (int p = 0; p < S_OUT; ++p) {
        float A = 0.f, P = 0.f, mc, bias_t, bias_r;
        if (TRANS) {
            const float4* wa4 = reinterpret_cast<const float4*>(wA4 + ((size_t)p * CC + c) * S_IN);
            const float4* wp4 = reinterpret_cast<const float4*>(wP4 + ((size_t)p * CC + c) * S_IN);
            #pragma unroll
            for (int q = 0; q < 7; ++q) {
                float4 wa = wa4[q];
                float4 wp = wp4[q];
                A = fmaf(wa.x, u[4*q+0], A);
                A = fmaf(wa.y, u[4*q+1], A);
                A = fmaf(wa.z, u[4*q+2], A);
                A = fmaf(wa.w, u[4*q+3], A);
                P = fmaf(wp.x, v[4*q+0], P);
                P = fmaf(wp.y, v[4*q+1], P);
                P = fmaf(wp.z, v[4*q+2], P);
                P = fmaf(wp.w, v[4*q+3], P);
            }
            mc     = mcoefT[p * CC + c];
            bias_t = biasv[(t  * S_OUT + p) * CC + c];
            bias_r = biasv[(tr * S_OUT + p) * CC + c];
        } else {
            const float* wa = wA_raw + (size_t)(c * S_OUT + p) * S_IN;
            const float* wp = wP_raw + (size_t)(c * S_OUT + p) * S_IN;
            float sw = 0.f;
            #pragma unroll
            for (int s = 0; s < S_IN; ++s) {
                float was = wa[s];
                A = fmaf(was, u[s], A);
                P = fmaf(wp[s], v[s], P);
                sw += was;
            }
            mc = 1.0f - sw;
            float ba = bAr[c * S_OUT + p], bp = bPr[c * S_OUT + p];
            bias_t = COEFP[t]  * bp + (t == 0 ? SQRT12F * ba : 0.f);
            bias_r = COEFP[tr] * bp;
        }
        const float mb = mean * mc;
        ob[(size_t)(p * WIN + t) * CC] = 0.5f * (A + P) + mb + bias_t;
        if (t != tr) {
            ob[(size_t)(p * WIN + tr) * CC] = 0.5f * (A - P) + mb + bias_r;
        }
    }
}

extern "C" void kernel_launch(void* const* d_in, const int* in_sizes, int n_in,
                              void* d_out, int out_size, void* d_ws, size_t ws_size,
                              hipStream_t stream) {
    const float* x  = (const float*)d_in[0];
    const float* wA = (const float*)d_in[1];
    const float* bA = (const float*)d_in[2];
    const float* wP = (const float*)d_in[3];
    const float* bP = (const float*)d_in[4];
    float* out = (float*)d_out;

    const size_t nW  = (size_t)S_OUT * CC * S_IN;   // 193088
    const size_t nM  = (size_t)S_OUT * CC;          // 6896
    const size_t nBv = (size_t)12 * S_OUT * CC;     // 82752
    const size_t need = (2 * nW + nM + nBv) * sizeof(float);

    dim3 grid(NTILES, BB);

    if (ws_size >= need) {
        float* wA4    = (float*)d_ws;
        float* wP4    = wA4 + nW;
        float* mcoefT = wP4 + nW;
        float* biasv  = mcoefT + nM;

        prep_w4<<<(int)((nW + 255) / 256), 256, 0, stream>>>(wA, wP, wA4, wP4);
        prep_mcoef<<<(int)((nM + 255) / 256), 256, 0, stream>>>(wA, mcoefT);
        prep_bias<<<(int)((nBv + 255) / 256), 256, 0, stream>>>(bA, bP, biasv);

        fused2<true><<<grid, 256, 0, stream>>>(
            x, wA4, wP4, mcoefT, biasv,
            nullptr, nullptr, nullptr, nullptr, out);
    } else {
        fused2<false><<<grid, 256, 0, stream>>>(
            x, nullptr, nullptr, nullptr, nullptr,
            wA, wP, bA, bP, out);
    }
}